// Round 1
// baseline (912.803 us; speedup 1.0000x reference)
//
#include <hip/hip_runtime.h>
#include <cstdint>
#include <cstddef>

// Depthwise conv1d (SAME, K=64) + bias + tanh.  B=32, L=32768, C=128.
// out[b][t][c] = tanh( bias[c] + sum_{k=0..63} x[b][t-31+k][c] * w[k][c] )
//
// Strategy: strip-persistent blocks + 64 KiB LDS ring (128 time-rows x 128 ch),
// async global->LDS staging one chunk ahead, 64 weights in VGPRs, triangular
// statically-unrolled FMA (16 outputs/thread/chunk, 79 LDS reads -> 1024 FMAs).

#define BQ 32
#define LQ 32768
#define CQ 128
#define KQ 64
#define NSTRIP 16
#define SLEN (LQ / NSTRIP)   // 2048
#define CHUNK 32
#define NCH (SLEN / CHUNK)   // 64
#define RING 128             // ring rows; ring bytes = 128*512 = 65536 exactly
#define RPT 16               // outputs per thread per chunk

typedef const __attribute__((address_space(1))) unsigned int gas1_u32;
typedef __attribute__((address_space(3))) unsigned int las3_u32;

__global__ __launch_bounds__(256, 2) void dwconv_tanh_kernel(
    const float* __restrict__ x, const float* __restrict__ kern,
    const float* __restrict__ bias, float* __restrict__ out) {
  __shared__ __align__(16) float xs[RING * CQ];  // row r at xs[r*128 + c]; 64 KiB

  const int tid = threadIdx.x;
  const int c   = tid & 127;
  const int h   = tid >> 7;                  // 0 or 1: which 16-row half of the chunk
  const int b   = blockIdx.x >> 4;           // / NSTRIP
  const int s   = blockIdx.x & (NSTRIP - 1);
  const int t_s = s * SLEN;
  const bool firstStrip = (s == 0);
  const bool lastStrip  = (s == NSTRIP - 1);

  const float* xb = x + (size_t)b * (LQ * CQ);

  // ---- per-channel weights (64 VGPRs) and bias ----
  float w[KQ];
#pragma unroll
  for (int k = 0; k < KQ; ++k) w[k] = kern[k * CQ + c];
  const float bc = bias[c];

  // ---- async stage of region j: times [t_s - 32 + 32j, +32) -> ring rows (96+32j)&127 .. +31
  auto stage = [&](int j) {
    const int T = t_s - 32 + 32 * j;
    const unsigned slot0 = (96u + 32u * (unsigned)j) & 127u;  // in {0,32,64,96}; no wrap in region
#pragma unroll
    for (int u = 0; u < 4; ++u) {
      const int off  = u * 4096 + tid * 16;  // byte offset within the 16 KiB region
      const int trow = off >> 9;             // 0..31
      const int cb   = off & 511;            // byte within 512 B row (multiple of 16)
      int t = T + trow;
      t = t < 0 ? 0 : (t >= LQ ? LQ - 1 : t);  // clamp: no OOB faults; garbage zero-fixed later
      const float* gp = xb + (size_t)t * CQ + (cb >> 2);
      float* lp = &xs[(slot0 + (unsigned)trow) * CQ + (unsigned)(cb >> 2)];
      __builtin_amdgcn_global_load_lds((gas1_u32*)gp, (las3_u32*)lp, 16, 0, 0);
    }
  };

  // ---- prologue: stage regions 0,1,2 = times [t_s-32, t_s+64) ----
  stage(0); stage(1); stage(2);
  __syncthreads();
  if (firstStrip) {
    // rows 96..127 hold times t_s-32..t_s-1 (< 0): zero them
#pragma unroll
    for (int u = 0; u < 16; ++u) xs[96 * CQ + u * 256 + tid] = 0.f;
    __syncthreads();
  }

  for (int i = 0; i < NCH; ++i) {
    // prefetch region j=i+3 (needed by chunk i+1); skip j=66, and j=65 on last strip (all t>=L)
    if ((i < NCH - 1) && !(lastStrip && i == NCH - 2)) stage(i + 3);

    if (lastStrip && i == NCH - 1) {
      // region j=65 (rows 0..31, times >= L): substitute zeros
#pragma unroll
      for (int u = 0; u < 16; ++u) xs[u * 256 + tid] = 0.f;
      __syncthreads();
    }

    // ---- compute chunk i: this thread -> outputs t0 .. t0+15 on channel c ----
    const int t0 = t_s + CHUNK * i + RPT * h;
    float acc[RPT];
#pragma unroll
    for (int r = 0; r < RPT; ++r) acc[r] = 0.f;

    // window times [t0-31, t0+47]; ring byte addr = ((t+128)&127)*512 + c*4, wrap via &65535
    const unsigned base = (((unsigned)(t0 + 97) & 127u) << 9) + ((unsigned)c << 2);
    const char* xsb = (const char*)xs;
#pragma unroll
    for (int ii = 0; ii < RPT + KQ - 1; ++ii) {  // 79 reads -> 1024 FMAs
      const unsigned a = (base + (unsigned)(ii * 512)) & 65535u;
      const float v = *(const float*)(xsb + a);
#pragma unroll
      for (int r = 0; r < RPT; ++r) {
        const int k = ii - r;
        if (k >= 0 && k < KQ) acc[r] = fmaf(w[k], v, acc[r]);
      }
    }

    // ---- epilogue: tanh(acc + bias) -> out (coalesced: lanes = consecutive c) ----
    float* op = out + ((size_t)b * LQ + (size_t)t0) * CQ + c;
#pragma unroll
    for (int r = 0; r < RPT; ++r) {
      const float z = acc[r] + bc;
      const float e = __expf(2.0f * z);                       // inf-safe form below
      op[(size_t)r * CQ] = 1.0f - 2.0f * __builtin_amdgcn_rcpf(e + 1.0f);
    }

    __syncthreads();  // drains this iter's stage (vmcnt) + protects ring rows
  }
}

extern "C" void kernel_launch(void* const* d_in, const int* in_sizes, int n_in,
                              void* d_out, int out_size, void* d_ws, size_t ws_size,
                              hipStream_t stream) {
  const float* x    = (const float*)d_in[0];
  const float* kern = (const float*)d_in[1];
  const float* bias = (const float*)d_in[2];
  float* out        = (float*)d_out;
  dwconv_tanh_kernel<<<dim3(BQ * NSTRIP), dim3(256), 0, stream>>>(x, kern, bias, out);
}